// Round 14
// baseline (161.170 us; speedup 1.0000x reference)
//
#include <hip/hip_runtime.h>

#define N_NODES 50000
#define N_EDGES 800000
#define NFEAT 512
#define NHID 128
#define NCLASS 64

#define SCAN_BLOCKS 49   // ceil(50000/1024)
#define ZERO_BLOCKS 49

using bf16x8 = __attribute__((ext_vector_type(8))) __bf16;
using f32x4  = __attribute__((ext_vector_type(4))) float;
using u16x8  = __attribute__((ext_vector_type(8))) unsigned short;
using u16x4  = __attribute__((ext_vector_type(4))) unsigned short;

__device__ __forceinline__ unsigned short f2bf(float f)
{
    unsigned u = __builtin_bit_cast(unsigned, f);
    unsigned r = (u + 0x7FFFu + ((u >> 16) & 1u)) >> 16;
    return (unsigned short)r;
}
__device__ __forceinline__ float bf2f(unsigned short b)
{
    return __builtin_bit_cast(float, (unsigned)b << 16);
}
__device__ __forceinline__ u16x4 cvt4(float4 f)
{
    u16x4 h;
    h[0] = __builtin_bit_cast(unsigned short, (__bf16)f.x);
    h[1] = __builtin_bit_cast(unsigned short, (__bf16)f.y);
    h[2] = __builtin_bit_cast(unsigned short, (__bf16)f.z);
    h[3] = __builtin_bit_cast(unsigned short, (__bf16)f.w);
    return h;
}

// ---- prep: zero counts + weight transpose/convert ---------------------------
__global__ void prep_kernel(int4* __restrict__ zp, int n4,
                            const float* __restrict__ W1, const float* __restrict__ W2,
                            unsigned short* __restrict__ W1t, unsigned short* __restrict__ W2t)
{
    const int b = blockIdx.x;
    if (b < ZERO_BLOCKS) {
        const int i = b * 256 + threadIdx.x;
        if (i < n4) zp[i] = make_int4(0, 0, 0, 0);
    } else {
        const int idx = (b - ZERO_BLOCKS) * 256 + threadIdx.x;
        if (idx < NFEAT * NHID) {
            const int n = idx / NFEAT, k = idx % NFEAT;
            W1t[idx] = f2bf(W1[k * NHID + n]);
        } else {
            const int j = idx - NFEAT * NHID;
            if (j < NHID * NCLASS) {
                const int n = j / NHID, k = j % NHID;
                W2t[j] = f2bf(W2[k * NCLASS + n]);
            }
        }
    }
}

// ---- hist + per-edge rank ---------------------------------------------------
__global__ void hist_rank_kernel(const int* __restrict__ er, int* __restrict__ counts,
                                 unsigned char* __restrict__ rank)
{
    int e = blockIdx.x * blockDim.x + threadIdx.x;
    if (e < N_EDGES) rank[e] = (unsigned char)atomicAdd(&counts[er[e]], 1);
}

// ---- single-kernel scan (block re-sums preceding counts; L2-cheap) ----------
__global__ __launch_bounds__(1024) void scan_fused(const int* __restrict__ counts,
                                                   int* __restrict__ row_ptr)
{
    __shared__ int tmp[1024];
    __shared__ int bpre;
    const int tid = threadIdx.x;
    const int b = blockIdx.x;
    const int gid = b * 1024 + tid;
    int pre = 0;
    for (int i = tid; i < b * 1024; i += 1024) pre += counts[i];
    tmp[tid] = pre;
    __syncthreads();
    #pragma unroll
    for (int off = 512; off > 0; off >>= 1) {
        if (tid < off) tmp[tid] += tmp[tid + off];
        __syncthreads();
    }
    if (tid == 0) bpre = tmp[0];
    __syncthreads();
    const int v = (gid < N_NODES) ? counts[gid] : 0;
    tmp[tid] = v;
    __syncthreads();
    #pragma unroll
    for (int off = 1; off < 1024; off <<= 1) {
        int t = (tid >= off) ? tmp[tid - off] : 0;
        __syncthreads();
        tmp[tid] += t;
        __syncthreads();
    }
    if (gid < N_NODES) row_ptr[gid] = bpre + tmp[tid] - v;
    if (gid == 0) row_ptr[N_NODES] = N_EDGES;
}

// ---- scatter: NONTEMPORAL streaming reads so dirty cv lines stay in L2 ------
__global__ void scatter_cv(const int* __restrict__ er, const int* __restrict__ ec,
                           const float* __restrict__ ev, const unsigned char* __restrict__ rank,
                           const int* __restrict__ row_ptr, unsigned* __restrict__ cv)
{
    int e = blockIdx.x * blockDim.x + threadIdx.x;
    if (e >= N_EDGES) return;
    const int r  = __builtin_nontemporal_load(&er[e]);
    const int c  = __builtin_nontemporal_load(&ec[e]);
    const float v = __builtin_nontemporal_load(&ev[e]);
    const unsigned char rk = __builtin_nontemporal_load(&rank[e]);
    const int pos = row_ptr[r] + (int)rk;
    cv[pos] = ((unsigned)f2bf(v) << 16) | (unsigned)c;
}

// ------------- GEMM1: fp32 A -> bf16, MFMA, bf16 out. 8 waves, dbuf pipeline -
__global__ __launch_bounds__(512) void gemm1_pipe(const float* __restrict__ A,
                                                  const unsigned short* __restrict__ Bt,
                                                  unsigned short* __restrict__ C, int M)
{
    constexpr int K = NFEAT, N = NHID, BM = 128, BK = 32, NSTEP = K / BK;
    constexpr int LDW = BK + 8;
    __shared__ unsigned short As[2][BM][LDW];
    __shared__ unsigned short Bs[2][N][LDW];

    const int tid  = threadIdx.x;
    const int wid  = tid >> 6;
    const int lane = tid & 63;
    const int lm   = lane & 15;
    const int lk   = (lane >> 4) * 8;
    const int m0   = blockIdx.x * BM;

    const int ar0 = tid >> 3;
    const int ac0 = (tid & 7) * 4;
    const int ga0 = (m0 + ar0      < M) ? (m0 + ar0)      : (M - 1);
    const int ga1 = (m0 + ar0 + 64 < M) ? (m0 + ar0 + 64) : (M - 1);
    const float* Arow0 = &A[(size_t)ga0 * K];
    const float* Arow1 = &A[(size_t)ga1 * K];
    const int bn = tid >> 2;
    const int bk = (tid & 3) * 8;
    const unsigned short* Brow = &Bt[(size_t)bn * K];

    f32x4 acc[8] = {};

    {
        float4 fa0 = *(const float4*)&Arow0[ac0];
        float4 fa1 = *(const float4*)&Arow1[ac0];
        u16x8  bv  = *(const u16x8*)&Brow[bk];
        *(u16x4*)&As[0][ar0][ac0]      = cvt4(fa0);
        *(u16x4*)&As[0][ar0 + 64][ac0] = cvt4(fa1);
        *(u16x8*)&Bs[0][bn][bk]        = bv;
    }
    __syncthreads();

    #pragma unroll
    for (int t = 0; t < NSTEP; ++t) {
        const int cur = t & 1;
        float4 na0, na1; u16x8 nb;
        if (t + 1 < NSTEP) {
            na0 = *(const float4*)&Arow0[(t + 1) * BK + ac0];
            na1 = *(const float4*)&Arow1[(t + 1) * BK + ac0];
            nb  = *(const u16x8*)&Brow[(t + 1) * BK + bk];
        }
        bf16x8 a = __builtin_bit_cast(bf16x8, *(const u16x8*)&As[cur][wid * 16 + lm][lk]);
        #pragma unroll
        for (int nf = 0; nf < 8; ++nf) {
            bf16x8 b = __builtin_bit_cast(bf16x8, *(const u16x8*)&Bs[cur][nf * 16 + lm][lk]);
            acc[nf] = __builtin_amdgcn_mfma_f32_16x16x32_bf16(a, b, acc[nf], 0, 0, 0);
        }
        if (t + 1 < NSTEP) {
            *(u16x4*)&As[cur ^ 1][ar0][ac0]      = cvt4(na0);
            *(u16x4*)&As[cur ^ 1][ar0 + 64][ac0] = cvt4(na1);
            *(u16x8*)&Bs[cur ^ 1][bn][bk]        = nb;
            __syncthreads();
        }
    }

    #pragma unroll
    for (int nf = 0; nf < 8; ++nf)
        #pragma unroll
        for (int r = 0; r < 4; ++r) {
            const int m = m0 + wid * 16 + (lane >> 4) * 4 + r;
            if (m < M) C[(size_t)m * N + nf * 16 + lm] =
                __builtin_bit_cast(unsigned short, (__bf16)acc[nf][r]);
        }
}

// ------------- GEMM2: bf16 A, bf16 out ---------------------------------------
template<int K, int N>
__global__ __launch_bounds__(256) void gemm_mfma_bf16a(const unsigned short* __restrict__ A,
                                                       const unsigned short* __restrict__ Bt,
                                                       unsigned short* __restrict__ C, int M)
{
    constexpr int BM = 128, BK = 32, NF = N / 16;
    constexpr int LDW = BK + 8;
    __shared__ unsigned short As[BM][LDW];
    __shared__ unsigned short Bs[N][LDW];

    const int tid  = threadIdx.x;
    const int wid  = tid >> 6;
    const int lane = tid & 63;
    const int lm   = lane & 15;
    const int lk   = (lane >> 4) * 8;
    const int m0   = blockIdx.x * BM;

    f32x4 acc[2][NF] = {};

    for (int k0 = 0; k0 < K; k0 += BK) {
        if (k0) __syncthreads();
        {
            #pragma unroll
            for (int c = 0; c < 2; ++c) {
                const int chunk = tid * 2 + c;
                const int r  = chunk >> 2;
                const int kc = (chunk & 3) * 8;
                const int m  = m0 + r;
                u16x8 v = {};
                if (m < M) v = *(const u16x8*)&A[(size_t)m * K + k0 + kc];
                *(u16x8*)&As[r][kc] = v;
            }
        }
        {
            constexpr int CH  = (N * BK / 8) / 256;
            constexpr int CPR = BK / 8;
            #pragma unroll
            for (int c = 0; c < CH; ++c) {
                const int chunk = tid * CH + c;
                const int n  = chunk / CPR;
                const int kc = (chunk % CPR) * 8;
                *(u16x8*)&Bs[n][kc] = *(const u16x8*)&Bt[(size_t)n * K + k0 + kc];
            }
        }
        __syncthreads();

        bf16x8 a[2];
        #pragma unroll
        for (int mf = 0; mf < 2; ++mf)
            a[mf] = __builtin_bit_cast(bf16x8, *(const u16x8*)&As[wid * 32 + mf * 16 + lm][lk]);
        #pragma unroll
        for (int nf = 0; nf < NF; ++nf) {
            bf16x8 b = __builtin_bit_cast(bf16x8, *(const u16x8*)&Bs[nf * 16 + lm][lk]);
            #pragma unroll
            for (int mf = 0; mf < 2; ++mf)
                acc[mf][nf] = __builtin_amdgcn_mfma_f32_16x16x32_bf16(a[mf], b, acc[mf][nf], 0, 0, 0);
        }
    }

    #pragma unroll
    for (int mf = 0; mf < 2; ++mf)
        #pragma unroll
        for (int nf = 0; nf < NF; ++nf)
            #pragma unroll
            for (int r = 0; r < 4; ++r) {
                const int m = m0 + wid * 32 + mf * 16 + (lane >> 4) * 4 + r;
                if (m < M) C[(size_t)m * N + nf * 16 + lm] =
                    __builtin_bit_cast(unsigned short, (__bf16)acc[mf][nf][r]);
            }
}

// ---- SpMM1: 2 edges/wave-step, 32 lanes/edge, 8B/lane gathers ---------------
__global__ __launch_bounds__(256) void spmm_bf16_h(const unsigned short* __restrict__ feat,
                                                   const int* __restrict__ row_ptr,
                                                   const unsigned* __restrict__ cv,
                                                   const float* __restrict__ bias,
                                                   unsigned short* __restrict__ out)
{
    const int wave = blockIdx.x * (blockDim.x >> 6) + (threadIdx.x >> 6);
    const int lane = threadIdx.x & 63;
    if (wave >= N_NODES) return;
    const int beg = row_ptr[wave];
    const int end = row_ptr[wave + 1];
    const int deg = end - beg;
    const int n1 = deg < 64 ? deg : 64;

    unsigned pcv = 0;
    if (lane < n1) pcv = cv[beg + lane];
    const int half = lane >> 5;
    const int qi   = (lane & 31) * 4;

    float ax[4][4] = {};
    for (int u = 0; u < n1; u += 8) {
        unsigned p[4];
        #pragma unroll
        for (int g = 0; g < 4; ++g) {
            const int idx = u + 2 * g + half;
            const int s = idx < n1 ? idx : 0;
            const unsigned t = __shfl(pcv, s, 64);
            p[g] = (idx < n1) ? t : 0u;
        }
        u16x4 w[4];
        #pragma unroll
        for (int g = 0; g < 4; ++g)
            w[g] = *(const u16x4*)&feat[(size_t)(p[g] & 0xFFFFu) * NHID + qi];
        #pragma unroll
        for (int g = 0; g < 4; ++g) {
            const float v = bf2f((unsigned short)(p[g] >> 16));
            #pragma unroll
            for (int j = 0; j < 4; ++j)
                ax[g][j] += v * bf2f(w[g][j]);
        }
    }
    for (int i = beg + 64 + half; i < end; i += 2) {
        const unsigned pp = cv[i];
        const float v = bf2f((unsigned short)(pp >> 16));
        const u16x4 w = *(const u16x4*)&feat[(size_t)(pp & 0xFFFFu) * NHID + qi];
        #pragma unroll
        for (int j = 0; j < 4; ++j) ax[0][j] += v * bf2f(w[j]);
    }

    float s[4];
    #pragma unroll
    for (int j = 0; j < 4; ++j) {
        s[j] = (ax[0][j] + ax[1][j]) + (ax[2][j] + ax[3][j]);
        s[j] += __shfl_xor(s[j], 32, 64);
    }
    if (half == 0) {
        const float4 bb = *(const float4*)&bias[qi];
        u16x4 o;
        o[0] = __builtin_bit_cast(unsigned short, (__bf16)fmaxf(s[0] + bb.x, 0.f));
        o[1] = __builtin_bit_cast(unsigned short, (__bf16)fmaxf(s[1] + bb.y, 0.f));
        o[2] = __builtin_bit_cast(unsigned short, (__bf16)fmaxf(s[2] + bb.z, 0.f));
        o[3] = __builtin_bit_cast(unsigned short, (__bf16)fmaxf(s[3] + bb.w, 0.f));
        *(u16x4*)&out[(size_t)wave * NHID + qi] = o;
    }
}

// ---- SpMM2: 4 edges/wave-step, 16 lanes/edge, 8B/lane gathers, fp32 out -----
__global__ __launch_bounds__(256) void spmm_bf16_o(const unsigned short* __restrict__ feat,
                                                   const int* __restrict__ row_ptr,
                                                   const unsigned* __restrict__ cv,
                                                   const float* __restrict__ bias,
                                                   float* __restrict__ out)
{
    const int wave = blockIdx.x * (blockDim.x >> 6) + (threadIdx.x >> 6);
    const int lane = threadIdx.x & 63;
    if (wave >= N_NODES) return;
    const int beg = row_ptr[wave];
    const int end = row_ptr[wave + 1];
    const int deg = end - beg;
    const int n1 = deg < 64 ? deg : 64;

    unsigned pcv = 0;
    if (lane < n1) pcv = cv[beg + lane];
    const int grp = lane >> 4;
    const int qi  = (lane & 15) * 4;

    float a[2][4] = {};
    for (int u = 0; u < n1; u += 8) {
        unsigned p[2];
        #pragma unroll
        for (int g = 0; g < 2; ++g) {
            const int idx = u + 4 * g + grp;
            const int s = idx < n1 ? idx : 0;
            const unsigned t = __shfl(pcv, s, 64);
            p[g] = (idx < n1) ? t : 0u;
        }
        u16x4 w[2];
        #pragma unroll
        for (int g = 0; g < 2; ++g)
            w[g] = *(const u16x4*)&feat[(size_t)(p[g] & 0xFFFFu) * NCLASS + qi];
        #pragma unroll
        for (int g = 0; g < 2; ++g) {
            const float v = bf2f((unsigned short)(p[g] >> 16));
            #pragma unroll
            for (int j = 0; j < 4; ++j)
                a[g][j] += v * bf2f(w[g][j]);
        }
    }
    for (int i = beg + 64 + grp; i < end; i += 4) {
        const unsigned pp = cv[i];
        const float v = bf2f((unsigned short)(pp >> 16));
        const u16x4 w = *(const u16x4*)&feat[(size_t)(pp & 0xFFFFu) * NCLASS + qi];
        #pragma unroll
        for (int j = 0; j < 4; ++j) a[0][j] += v * bf2f(w[j]);
    }

    float s[4];
    #pragma unroll
    for (int j = 0; j < 4; ++j) {
        s[j] = a[0][j] + a[1][j];
        s[j] += __shfl_xor(s[j], 16, 64);
        s[j] += __shfl_xor(s[j], 32, 64);
    }
    if (lane < 16) {
        const float4 bb = *(const float4*)&bias[qi];
        float4 o = make_float4(s[0] + bb.x, s[1] + bb.y, s[2] + bb.z, s[3] + bb.w);
        *(float4*)&out[(size_t)wave * NCLASS + qi] = o;
    }
}

extern "C" void kernel_launch(void* const* d_in, const int* in_sizes, int n_in,
                              void* d_out, int out_size, void* d_ws, size_t ws_size,
                              hipStream_t stream)
{
    const float* x  = (const float*)d_in[0];
    const float* W1 = (const float*)d_in[1];
    const float* b1 = (const float*)d_in[2];
    const float* W2 = (const float*)d_in[3];
    const float* b2 = (const float*)d_in[4];
    const float* ev = (const float*)d_in[5];
    const int*   er = (const int*)d_in[6];
    const int*   ec = (const int*)d_in[7];
    float* out = (float*)d_out;

    // ---- workspace layout ----
    unsigned* cv = (unsigned*)d_ws;                           // 800,000 u32
    unsigned char* rank = (unsigned char*)(cv + N_EDGES);     // 800,000 u8
    unsigned short* XW1  = (unsigned short*)(rank + N_EDGES); // 6,400,000 u16
    unsigned short* Hpre = XW1 + (size_t)N_NODES * NHID;      // 6,400,000 u16
    int* row_ptr = (int*)(Hpre + (size_t)N_NODES * NHID);     // 50016
    int* counts  = row_ptr + 50016;                           // 50016
    unsigned short* W1t = (unsigned short*)(counts + 50016);  // 65536 u16
    unsigned short* W2t = W1t + NFEAT * NHID;                 // 8192 u16

    unsigned short* HW2 = XW1;  // reuses XW1 slot

    // ---- prep: zero counts + convert weights ----
    {
        const int n4 = 50016 / 4;
        const int conv_blocks = (NFEAT * NHID + NHID * NCLASS + 255) / 256;
        prep_kernel<<<ZERO_BLOCKS + conv_blocks, 256, 0, stream>>>(
            (int4*)counts, n4, W1, W2, W1t, W2t);
    }
    // ---- CSR build ----
    hist_rank_kernel<<<(N_EDGES + 255) / 256, 256, 0, stream>>>(er, counts, rank);
    scan_fused<<<SCAN_BLOCKS, 1024, 0, stream>>>(counts, row_ptr);
    scatter_cv<<<(N_EDGES + 255) / 256, 256, 0, stream>>>(er, ec, ev, rank, row_ptr, cv);

    // ---- layer 1 ----
    gemm1_pipe<<<(N_NODES + 127) / 128, 512, 0, stream>>>(x, W1t, XW1, N_NODES);
    spmm_bf16_h<<<(N_NODES + 3) / 4, 256, 0, stream>>>(XW1, row_ptr, cv, b1, Hpre);
    // ---- layer 2 ----
    gemm_mfma_bf16a<NHID, NCLASS><<<(N_NODES + 127) / 128, 256, 0, stream>>>(Hpre, W2t, HW2, N_NODES);
    spmm_bf16_o<<<(N_NODES + 3) / 4, 256, 0, stream>>>(HW2, row_ptr, cv, b2, out);
}

// Round 15
// 148.018 us; speedup vs baseline: 1.0889x; 1.0889x over previous
//
#include <hip/hip_runtime.h>

#define N_NODES 50000
#define N_EDGES 800000
#define NFEAT 512
#define NHID 128
#define NCLASS 64

#define SCAN_BLOCKS 49   // ceil(50000/1024)
#define ZERO_BLOCKS 49   // (50016+64)/4 int4s / 256 -> 49 blocks

using bf16x8 = __attribute__((ext_vector_type(8))) __bf16;
using f32x4  = __attribute__((ext_vector_type(4))) float;
using u16x8  = __attribute__((ext_vector_type(8))) unsigned short;
using u16x4  = __attribute__((ext_vector_type(4))) unsigned short;

__device__ __forceinline__ unsigned short f2bf(float f)
{
    unsigned u = __builtin_bit_cast(unsigned, f);
    unsigned r = (u + 0x7FFFu + ((u >> 16) & 1u)) >> 16;
    return (unsigned short)r;
}
__device__ __forceinline__ float bf2f(unsigned short b)
{
    return __builtin_bit_cast(float, (unsigned)b << 16);
}
__device__ __forceinline__ u16x4 cvt4(float4 f)
{
    u16x4 h;
    h[0] = __builtin_bit_cast(unsigned short, (__bf16)f.x);
    h[1] = __builtin_bit_cast(unsigned short, (__bf16)f.y);
    h[2] = __builtin_bit_cast(unsigned short, (__bf16)f.z);
    h[3] = __builtin_bit_cast(unsigned short, (__bf16)f.w);
    return h;
}

// ---- prep: zero counts|bsums + weight transpose/convert ---------------------
__global__ void prep_kernel(int4* __restrict__ zp, int n4,
                            const float* __restrict__ W1, const float* __restrict__ W2,
                            unsigned short* __restrict__ W1t, unsigned short* __restrict__ W2t)
{
    const int b = blockIdx.x;
    if (b < ZERO_BLOCKS) {
        const int i = b * 256 + threadIdx.x;
        if (i < n4) zp[i] = make_int4(0, 0, 0, 0);
    } else {
        const int idx = (b - ZERO_BLOCKS) * 256 + threadIdx.x;
        if (idx < NFEAT * NHID) {
            const int n = idx / NFEAT, k = idx % NFEAT;
            W1t[idx] = f2bf(W1[k * NHID + n]);
        } else {
            const int j = idx - NFEAT * NHID;
            if (j < NHID * NCLASS) {
                const int n = j / NHID, k = j % NHID;
                W2t[j] = f2bf(W2[k * NCLASS + n]);
            }
        }
    }
}

// ------------- GEMM1: fp32 A -> bf16, MFMA, bf16 out. 8 waves, dbuf pipeline -
__global__ __launch_bounds__(512) void gemm1_pipe(const float* __restrict__ A,
                                                  const unsigned short* __restrict__ Bt,
                                                  unsigned short* __restrict__ C, int M)
{
    constexpr int K = NFEAT, N = NHID, BM = 128, BK = 32, NSTEP = K / BK;
    constexpr int LDW = BK + 8;
    __shared__ unsigned short As[2][BM][LDW];
    __shared__ unsigned short Bs[2][N][LDW];

    const int tid  = threadIdx.x;
    const int wid  = tid >> 6;
    const int lane = tid & 63;
    const int lm   = lane & 15;
    const int lk   = (lane >> 4) * 8;
    const int m0   = blockIdx.x * BM;

    const int ar0 = tid >> 3;
    const int ac0 = (tid & 7) * 4;
    const int ga0 = (m0 + ar0      < M) ? (m0 + ar0)      : (M - 1);
    const int ga1 = (m0 + ar0 + 64 < M) ? (m0 + ar0 + 64) : (M - 1);
    const float* Arow0 = &A[(size_t)ga0 * K];
    const float* Arow1 = &A[(size_t)ga1 * K];
    const int bn = tid >> 2;
    const int bk = (tid & 3) * 8;
    const unsigned short* Brow = &Bt[(size_t)bn * K];

    f32x4 acc[8] = {};

    {
        float4 fa0 = *(const float4*)&Arow0[ac0];
        float4 fa1 = *(const float4*)&Arow1[ac0];
        u16x8  bv  = *(const u16x8*)&Brow[bk];
        *(u16x4*)&As[0][ar0][ac0]      = cvt4(fa0);
        *(u16x4*)&As[0][ar0 + 64][ac0] = cvt4(fa1);
        *(u16x8*)&Bs[0][bn][bk]        = bv;
    }
    __syncthreads();

    #pragma unroll
    for (int t = 0; t < NSTEP; ++t) {
        const int cur = t & 1;
        float4 na0, na1; u16x8 nb;
        if (t + 1 < NSTEP) {
            na0 = *(const float4*)&Arow0[(t + 1) * BK + ac0];
            na1 = *(const float4*)&Arow1[(t + 1) * BK + ac0];
            nb  = *(const u16x8*)&Brow[(t + 1) * BK + bk];
        }
        bf16x8 a = __builtin_bit_cast(bf16x8, *(const u16x8*)&As[cur][wid * 16 + lm][lk]);
        #pragma unroll
        for (int nf = 0; nf < 8; ++nf) {
            bf16x8 b = __builtin_bit_cast(bf16x8, *(const u16x8*)&Bs[cur][nf * 16 + lm][lk]);
            acc[nf] = __builtin_amdgcn_mfma_f32_16x16x32_bf16(a, b, acc[nf], 0, 0, 0);
        }
        if (t + 1 < NSTEP) {
            *(u16x4*)&As[cur ^ 1][ar0][ac0]      = cvt4(na0);
            *(u16x4*)&As[cur ^ 1][ar0 + 64][ac0] = cvt4(na1);
            *(u16x8*)&Bs[cur ^ 1][bn][bk]        = nb;
            __syncthreads();
        }
    }

    #pragma unroll
    for (int nf = 0; nf < 8; ++nf)
        #pragma unroll
        for (int r = 0; r < 4; ++r) {
            const int m = m0 + wid * 16 + (lane >> 4) * 4 + r;
            if (m < M) C[(size_t)m * N + nf * 16 + lm] =
                __builtin_bit_cast(unsigned short, (__bf16)acc[nf][r]);
        }
}

// ------------- GEMM2: bf16 A, bf16 out ---------------------------------------
template<int K, int N>
__global__ __launch_bounds__(256) void gemm_mfma_bf16a(const unsigned short* __restrict__ A,
                                                       const unsigned short* __restrict__ Bt,
                                                       unsigned short* __restrict__ C, int M)
{
    constexpr int BM = 128, BK = 32, NF = N / 16;
    constexpr int LDW = BK + 8;
    __shared__ unsigned short As[BM][LDW];
    __shared__ unsigned short Bs[N][LDW];

    const int tid  = threadIdx.x;
    const int wid  = tid >> 6;
    const int lane = tid & 63;
    const int lm   = lane & 15;
    const int lk   = (lane >> 4) * 8;
    const int m0   = blockIdx.x * BM;

    f32x4 acc[2][NF] = {};

    for (int k0 = 0; k0 < K; k0 += BK) {
        if (k0) __syncthreads();
        {
            #pragma unroll
            for (int c = 0; c < 2; ++c) {
                const int chunk = tid * 2 + c;
                const int r  = chunk >> 2;
                const int kc = (chunk & 3) * 8;
                const int m  = m0 + r;
                u16x8 v = {};
                if (m < M) v = *(const u16x8*)&A[(size_t)m * K + k0 + kc];
                *(u16x8*)&As[r][kc] = v;
            }
        }
        {
            constexpr int CH  = (N * BK / 8) / 256;
            constexpr int CPR = BK / 8;
            #pragma unroll
            for (int c = 0; c < CH; ++c) {
                const int chunk = tid * CH + c;
                const int n  = chunk / CPR;
                const int kc = (chunk % CPR) * 8;
                *(u16x8*)&Bs[n][kc] = *(const u16x8*)&Bt[(size_t)n * K + k0 + kc];
            }
        }
        __syncthreads();

        bf16x8 a[2];
        #pragma unroll
        for (int mf = 0; mf < 2; ++mf)
            a[mf] = __builtin_bit_cast(bf16x8, *(const u16x8*)&As[wid * 32 + mf * 16 + lm][lk]);
        #pragma unroll
        for (int nf = 0; nf < NF; ++nf) {
            bf16x8 b = __builtin_bit_cast(bf16x8, *(const u16x8*)&Bs[nf * 16 + lm][lk]);
            #pragma unroll
            for (int mf = 0; mf < 2; ++mf)
                acc[mf][nf] = __builtin_amdgcn_mfma_f32_16x16x32_bf16(a[mf], b, acc[mf][nf], 0, 0, 0);
        }
    }

    #pragma unroll
    for (int mf = 0; mf < 2; ++mf)
        #pragma unroll
        for (int nf = 0; nf < NF; ++nf)
            #pragma unroll
            for (int r = 0; r < 4; ++r) {
                const int m = m0 + wid * 32 + mf * 16 + (lane >> 4) * 4 + r;
                if (m < M) C[(size_t)m * N + nf * 16 + lm] =
                    __builtin_bit_cast(unsigned short, (__bf16)acc[mf][nf][r]);
            }
}

// ---- hist + per-edge rank ---------------------------------------------------
__global__ void hist_rank_kernel(const int* __restrict__ er, int* __restrict__ counts,
                                 unsigned char* __restrict__ rank)
{
    int e = blockIdx.x * blockDim.x + threadIdx.x;
    if (e < N_EDGES) rank[e] = (unsigned char)atomicAdd(&counts[er[e]], 1);
}

__global__ __launch_bounds__(1024) void scan_blocks(const int* __restrict__ counts,
                                                    int* __restrict__ row_ptr,
                                                    int* __restrict__ bsums)
{
    __shared__ int tmp[1024];
    const int tid = threadIdx.x;
    const int gid = blockIdx.x * 1024 + tid;
    const int v = (gid < N_NODES) ? counts[gid] : 0;
    tmp[tid] = v;
    __syncthreads();
    #pragma unroll
    for (int off = 1; off < 1024; off <<= 1) {
        int t = (tid >= off) ? tmp[tid - off] : 0;
        __syncthreads();
        tmp[tid] += t;
        __syncthreads();
    }
    if (gid < N_NODES) row_ptr[gid] = tmp[tid] - v;
    if (tid == 1023) bsums[blockIdx.x] = tmp[1023];
}

// ---- add_offsets with inline bsums scan -------------------------------------
__global__ __launch_bounds__(1024) void add_offsets2(int* __restrict__ row_ptr,
                                                     const int* __restrict__ bsums)
{
    __shared__ int soff;
    if (threadIdx.x < 64) {
        const int lane = threadIdx.x;
        const int orig = (lane < SCAN_BLOCKS) ? bsums[lane] : 0;
        int v = orig;
        #pragma unroll
        for (int off = 1; off < 64; off <<= 1) {
            int t = __shfl_up(v, off, 64);
            if (lane >= off) v += t;
        }
        if (lane == (int)blockIdx.x) soff = v - orig;
    }
    __syncthreads();
    const int gid = blockIdx.x * 1024 + threadIdx.x;
    if (gid < N_NODES) row_ptr[gid] += soff;
    if (gid == 0) row_ptr[N_NODES] = N_EDGES;
}

// ---- scatter: one packed 4B store per edge ---------------------------------
__global__ void scatter_cv(const int* __restrict__ er, const int* __restrict__ ec,
                           const float* __restrict__ ev, const unsigned char* __restrict__ rank,
                           const int* __restrict__ row_ptr, unsigned* __restrict__ cv)
{
    int e = blockIdx.x * blockDim.x + threadIdx.x;
    if (e >= N_EDGES) return;
    const int r = er[e];
    const int pos = row_ptr[r] + (int)rank[e];
    cv[pos] = ((unsigned)f2bf(ev[e]) << 16) | (unsigned)ec[e];
}

// ---- SpMM1: 2 edges/wave-step, 32 lanes/edge, 8B/lane gathers ---------------
__global__ __launch_bounds__(256) void spmm_bf16_h(const unsigned short* __restrict__ feat,
                                                   const int* __restrict__ row_ptr,
                                                   const unsigned* __restrict__ cv,
                                                   const float* __restrict__ bias,
                                                   unsigned short* __restrict__ out)
{
    const int wave = blockIdx.x * (blockDim.x >> 6) + (threadIdx.x >> 6);
    const int lane = threadIdx.x & 63;
    if (wave >= N_NODES) return;
    const int beg = row_ptr[wave];
    const int end = row_ptr[wave + 1];
    const int deg = end - beg;
    const int n1 = deg < 64 ? deg : 64;

    unsigned pcv = 0;
    if (lane < n1) pcv = cv[beg + lane];
    const int half = lane >> 5;
    const int qi   = (lane & 31) * 4;

    float ax[4][4] = {};
    for (int u = 0; u < n1; u += 8) {
        unsigned p[4];
        #pragma unroll
        for (int g = 0; g < 4; ++g) {
            const int idx = u + 2 * g + half;
            const int s = idx < n1 ? idx : 0;
            const unsigned t = __shfl(pcv, s, 64);
            p[g] = (idx < n1) ? t : 0u;
        }
        u16x4 w[4];
        #pragma unroll
        for (int g = 0; g < 4; ++g)
            w[g] = *(const u16x4*)&feat[(size_t)(p[g] & 0xFFFFu) * NHID + qi];
        #pragma unroll
        for (int g = 0; g < 4; ++g) {
            const float v = bf2f((unsigned short)(p[g] >> 16));
            #pragma unroll
            for (int j = 0; j < 4; ++j)
                ax[g][j] += v * bf2f(w[g][j]);
        }
    }
    for (int i = beg + 64 + half; i < end; i += 2) {
        const unsigned pp = cv[i];
        const float v = bf2f((unsigned short)(pp >> 16));
        const u16x4 w = *(const u16x4*)&feat[(size_t)(pp & 0xFFFFu) * NHID + qi];
        #pragma unroll
        for (int j = 0; j < 4; ++j) ax[0][j] += v * bf2f(w[j]);
    }

    float s[4];
    #pragma unroll
    for (int j = 0; j < 4; ++j) {
        s[j] = (ax[0][j] + ax[1][j]) + (ax[2][j] + ax[3][j]);
        s[j] += __shfl_xor(s[j], 32, 64);
    }
    if (half == 0) {
        const float4 bb = *(const float4*)&bias[qi];
        u16x4 o;
        o[0] = __builtin_bit_cast(unsigned short, (__bf16)fmaxf(s[0] + bb.x, 0.f));
        o[1] = __builtin_bit_cast(unsigned short, (__bf16)fmaxf(s[1] + bb.y, 0.f));
        o[2] = __builtin_bit_cast(unsigned short, (__bf16)fmaxf(s[2] + bb.z, 0.f));
        o[3] = __builtin_bit_cast(unsigned short, (__bf16)fmaxf(s[3] + bb.w, 0.f));
        *(u16x4*)&out[(size_t)wave * NHID + qi] = o;
    }
}

// ---- SpMM2: 4 edges/wave-step, 16 lanes/edge, 8B/lane gathers, fp32 out -----
__global__ __launch_bounds__(256) void spmm_bf16_o(const unsigned short* __restrict__ feat,
                                                   const int* __restrict__ row_ptr,
                                                   const unsigned* __restrict__ cv,
                                                   const float* __restrict__ bias,
                                                   float* __restrict__ out)
{
    const int wave = blockIdx.x * (blockDim.x >> 6) + (threadIdx.x >> 6);
    const int lane = threadIdx.x & 63;
    if (wave >= N_NODES) return;
    const int beg = row_ptr[wave];
    const int end = row_ptr[wave + 1];
    const int deg = end - beg;
    const int n1 = deg < 64 ? deg : 64;

    unsigned pcv = 0;
    if (lane < n1) pcv = cv[beg + lane];
    const int grp = lane >> 4;
    const int qi  = (lane & 15) * 4;

    float a[2][4] = {};
    for (int u = 0; u < n1; u += 8) {
        unsigned p[2];
        #pragma unroll
        for (int g = 0; g < 2; ++g) {
            const int idx = u + 4 * g + grp;
            const int s = idx < n1 ? idx : 0;
            const unsigned t = __shfl(pcv, s, 64);
            p[g] = (idx < n1) ? t : 0u;
        }
        u16x4 w[2];
        #pragma unroll
        for (int g = 0; g < 2; ++g)
            w[g] = *(const u16x4*)&feat[(size_t)(p[g] & 0xFFFFu) * NCLASS + qi];
        #pragma unroll
        for (int g = 0; g < 2; ++g) {
            const float v = bf2f((unsigned short)(p[g] >> 16));
            #pragma unroll
            for (int j = 0; j < 4; ++j)
                a[g][j] += v * bf2f(w[g][j]);
        }
    }
    for (int i = beg + 64 + grp; i < end; i += 4) {
        const unsigned pp = cv[i];
        const float v = bf2f((unsigned short)(pp >> 16));
        const u16x4 w = *(const u16x4*)&feat[(size_t)(pp & 0xFFFFu) * NCLASS + qi];
        #pragma unroll
        for (int j = 0; j < 4; ++j) a[0][j] += v * bf2f(w[j]);
    }

    float s[4];
    #pragma unroll
    for (int j = 0; j < 4; ++j) {
        s[j] = a[0][j] + a[1][j];
        s[j] += __shfl_xor(s[j], 16, 64);
        s[j] += __shfl_xor(s[j], 32, 64);
    }
    if (lane < 16) {
        const float4 bb = *(const float4*)&bias[qi];
        float4 o = make_float4(s[0] + bb.x, s[1] + bb.y, s[2] + bb.z, s[3] + bb.w);
        *(float4*)&out[(size_t)wave * NCLASS + qi] = o;
    }
}

extern "C" void kernel_launch(void* const* d_in, const int* in_sizes, int n_in,
                              void* d_out, int out_size, void* d_ws, size_t ws_size,
                              hipStream_t stream)
{
    const float* x  = (const float*)d_in[0];
    const float* W1 = (const float*)d_in[1];
    const float* b1 = (const float*)d_in[2];
    const float* W2 = (const float*)d_in[3];
    const float* b2 = (const float*)d_in[4];
    const float* ev = (const float*)d_in[5];
    const int*   er = (const int*)d_in[6];
    const int*   ec = (const int*)d_in[7];
    float* out = (float*)d_out;

    // ---- workspace layout ----
    unsigned* cv = (unsigned*)d_ws;                           // 800,000 u32
    unsigned char* rank = (unsigned char*)(cv + N_EDGES);     // 800,000 u8
    unsigned short* XW1  = (unsigned short*)(rank + N_EDGES); // 6,400,000 u16
    unsigned short* Hpre = XW1 + (size_t)N_NODES * NHID;      // 6,400,000 u16
    int* row_ptr = (int*)(Hpre + (size_t)N_NODES * NHID);     // 50016
    int* counts  = row_ptr + 50016;                           // 50016
    int* bsums   = counts + 50016;                            // 64
    unsigned short* W1t = (unsigned short*)(bsums + 64);      // 65536 u16
    unsigned short* W2t = W1t + NFEAT * NHID;                 // 8192 u16

    unsigned short* HW2 = XW1;  // reuses XW1 slot

    // ---- prep ----
    {
        const int n4 = (50016 + 64) / 4;
        const int conv_blocks = (NFEAT * NHID + NHID * NCLASS + 255) / 256;
        prep_kernel<<<ZERO_BLOCKS + conv_blocks, 256, 0, stream>>>(
            (int4*)counts, n4, W1, W2, W1t, W2t);
    }
    // ---- CSR build ----
    hist_rank_kernel<<<(N_EDGES + 255) / 256, 256, 0, stream>>>(er, counts, rank);
    scan_blocks<<<SCAN_BLOCKS, 1024, 0, stream>>>(counts, row_ptr, bsums);
    add_offsets2<<<SCAN_BLOCKS, 1024, 0, stream>>>(row_ptr, bsums);
    scatter_cv<<<(N_EDGES + 255) / 256, 256, 0, stream>>>(er, ec, ev, rank, row_ptr, cv);

    // ---- layer 1 ----
    gemm1_pipe<<<(N_NODES + 127) / 128, 512, 0, stream>>>(x, W1t, XW1, N_NODES);
    spmm_bf16_h<<<(N_NODES + 3) / 4, 256, 0, stream>>>(XW1, row_ptr, cv, b1, Hpre);
    // ---- layer 2 ----
    gemm_mfma_bf16a<NHID, NCLASS><<<(N_NODES + 127) / 128, 256, 0, stream>>>(Hpre, W2t, HW2, N_NODES);
    spmm_bf16_o<<<(N_NODES + 3) / 4, 256, 0, stream>>>(HW2, row_ptr, cv, b2, out);
}